// Round 4
// baseline (91.422 us; speedup 1.0000x reference)
//
#include <hip/hip_runtime.h>

// 4-qubit / 3-layer VQC, B = 2^20.
//
// Key identity: with merged angle th_w = patch_w + params[0,w,0], every
// output is EXACTLY multilinear in t_w = (1, cos th_w, sin th_w):
//     o_w = sum_{a,b,c,d} T^w[a,b,c,d] * t0_a t1_b t2_c t3_d
// because the batch-dependent part of the circuit is only the initial
// product state x(cos th/2, sin th/2 e^{i phi_w}) and probabilities are
// quadratic per qubit: span{cos^2(th/2), sin(th/2)cos(th/2), sin^2(th/2)}
// = affine span{1, cos th, sin th}. Everything else (layer-0 RZ phases,
// CNOTs, layers 1-2) is batch-uniform and folds into T.
//
// Setup kernel (1 block): simulate the full reference circuit on the 3^4
// grid th in {0, pi/2, pi} (exact half-angle trig), then invert the
// evaluation map mode-by-mode to get T (4 x 81 floats in d_ws).
// Main kernel: 4 sincos + 8 mults + 360 v_fmac_f32 with uniform (SGPR)
// coefficients per thread.

__global__ void vqc_setup(const float* __restrict__ params,
                          float* __restrict__ ws) {
    __shared__ float bufA[81][4];
    __shared__ float bufB[81][4];
    const int tid = threadIdx.x;

    if (tid < 81) {
        const int g = tid;
        const int d0 = g / 27, d1 = (g / 9) % 3, d2 = (g / 3) % 3, d3 = g % 3;
        // half-angle trig of th in {0, pi/2, pi} — exact
        const float chalf[3] = {1.0f, 0.70710678118654752f, 0.0f};
        const float shalf[3] = {0.0f, 0.70710678118654752f, 1.0f};
        const float ch[4] = {chalf[d0], chalf[d1], chalf[d2], chalf[d3]};
        const float sh[4] = {shalf[d0], shalf[d1], shalf[d2], shalf[d3]};

        float re[16], im[16];
        for (int k = 0; k < 16; ++k) {
            float a = ((k >> 3) & 1) ? sh[0] : ch[0];
            a *= ((k >> 2) & 1) ? sh[1] : ch[1];
            a *= ((k >> 1) & 1) ? sh[2] : ch[2];
            a *= (k & 1) ? sh[3] : ch[3];
            re[k] = a;
            im[k] = 0.0f;
        }

        // ---- layer 0: RZ on each wire (RY already merged into grid angle) ----
        for (int w = 0; w < 4; ++w) {
            const int m = 8 >> w;
            const float t = params[w * 2 + 1];
            const float cz = cosf(0.5f * t), sz = sinf(0.5f * t);
            for (int k = 0; k < 16; ++k) {
                const float r = re[k], q = im[k];
                if (k & m) { re[k] = r * cz - q * sz; im[k] = q * cz + r * sz; }
                else       { re[k] = r * cz + q * sz; im[k] = q * cz - r * sz; }
            }
        }
        // CNOT chain
        for (int w = 0; w < 3; ++w) {
            const int cm = 8 >> w, tm = 8 >> (w + 1);
            for (int b = 0; b < 16; ++b) {
                if ((b & cm) && !(b & tm)) {
                    const int j = b | tm;
                    float tr = re[b]; re[b] = re[j]; re[j] = tr;
                    float ti = im[b]; im[b] = im[j]; im[j] = ti;
                }
            }
        }

        // ---- layers 1, 2 ----
        for (int l = 1; l < 3; ++l) {
            for (int w = 0; w < 4; ++w) {
                const int m = 8 >> w;
                const float ty = params[(l * 4 + w) * 2 + 0];
                const float tz = params[(l * 4 + w) * 2 + 1];
                const float cy = cosf(0.5f * ty), sy = sinf(0.5f * ty);
                const float cz = cosf(0.5f * tz), sz = sinf(0.5f * tz);
                for (int b = 0; b < 16; ++b) {
                    if (b & m) continue;
                    const int j = b | m;
                    const float r0 = re[b], r1 = re[j];
                    const float i0 = im[b], i1 = im[j];
                    re[b] = cy * r0 - sy * r1;  re[j] = sy * r0 + cy * r1;
                    im[b] = cy * i0 - sy * i1;  im[j] = sy * i0 + cy * i1;
                }
                for (int k = 0; k < 16; ++k) {
                    const float r = re[k], q = im[k];
                    if (k & m) { re[k] = r * cz - q * sz; im[k] = q * cz + r * sz; }
                    else       { re[k] = r * cz + q * sz; im[k] = q * cz - r * sz; }
                }
            }
            for (int w = 0; w < 3; ++w) {
                const int cm = 8 >> w, tm = 8 >> (w + 1);
                for (int b = 0; b < 16; ++b) {
                    if ((b & cm) && !(b & tm)) {
                        const int j = b | tm;
                        float tr = re[b]; re[b] = re[j]; re[j] = tr;
                        float ti = im[b]; im[b] = im[j]; im[j] = ti;
                    }
                }
            }
        }

        // ---- expvals ----
        float ev[4] = {0.f, 0.f, 0.f, 0.f};
        for (int k = 0; k < 16; ++k) {
            const float pk = re[k] * re[k] + im[k] * im[k];
            ev[0] += (k & 8) ? -pk : pk;
            ev[1] += (k & 4) ? -pk : pk;
            ev[2] += (k & 2) ? -pk : pk;
            ev[3] += (k & 1) ? -pk : pk;
        }
        for (int w = 0; w < 4; ++w) bufA[g][w] = ev[w];
    }
    __syncthreads();

    // ---- invert evaluation map, one mode at a time ----
    // eval points th={0,pi/2,pi} -> M rows (1,1,0),(1,0,1),(1,-1,0);
    // Minv = [[.5,0,.5],[.5,0,-.5],[-.5,1,-.5]]
    const float Minv[3][3] = {{0.5f, 0.0f, 0.5f},
                              {0.5f, 0.0f, -0.5f},
                              {-0.5f, 1.0f, -0.5f}};
    const int strides[4] = {27, 9, 3, 1};
    for (int mo = 0; mo < 4; ++mo) {
        const int st = strides[mo];
        float (*src)[4] = (mo & 1) ? bufB : bufA;
        float (*dst)[4] = (mo & 1) ? bufA : bufB;
        for (int idx = tid; idx < 324; idx += blockDim.x) {
            const int w = idx & 3, pos = idx >> 2;
            const int dm = (pos / st) % 3;
            const int base = pos - dm * st;
            const float v = Minv[dm][0] * src[base][w]
                          + Minv[dm][1] * src[base + st][w]
                          + Minv[dm][2] * src[base + 2 * st][w];
            if (mo == 3) ws[w * 81 + pos] = v;   // pos = 9*(3d0+d1)+(3d2+d3)
            else dst[pos][w] = v;
        }
        __syncthreads();
    }
}

__global__ __launch_bounds__(256) void vqc_main(const float* __restrict__ patch,
                                                const float* __restrict__ params,
                                                const float* __restrict__ ws,
                                                float* __restrict__ out,
                                                const int B) {
    const int i = blockIdx.x * blockDim.x + threadIdx.x;
    if (i >= B) return;

    const float4 p = reinterpret_cast<const float4*>(patch)[i];

    // full merged angles (uniform offsets via s_load)
    float c0, s0, c1, s1, c2, s2, c3, s3;
    __sincosf(p.x + params[0], &s0, &c0);
    __sincosf(p.y + params[2], &s1, &c1);
    __sincosf(p.z + params[4], &s2, &c2);
    __sincosf(p.w + params[6], &s3, &c3);

    // v01[3a+b] = t0[a]*t1[b], t = (1, cos, sin); likewise v23
    float v01[9], v23[9];
    v01[0] = 1.0f; v01[1] = c1;      v01[2] = s1;
    v01[3] = c0;   v01[4] = c0 * c1; v01[5] = c0 * s1;
    v01[6] = s0;   v01[7] = s0 * c1; v01[8] = s0 * s1;
    v23[0] = 1.0f; v23[1] = c3;      v23[2] = s3;
    v23[3] = c2;   v23[4] = c2 * c3; v23[5] = c2 * s3;
    v23[6] = s2;   v23[7] = s2 * c3; v23[8] = s2 * s3;

    const float* __restrict__ T0 = ws;
    const float* __restrict__ T1 = ws + 81;
    const float* __restrict__ T2 = ws + 162;
    const float* __restrict__ T3 = ws + 243;

    float o0 = 0.f, o1 = 0.f, o2 = 0.f, o3 = 0.f;
#pragma unroll
    for (int a = 0; a < 9; ++a) {
        float y0 = 0.f, y1 = 0.f, y2 = 0.f, y3 = 0.f;
#pragma unroll
        for (int b = 0; b < 9; ++b) {
            y0 = fmaf(T0[9 * a + b], v23[b], y0);
            y1 = fmaf(T1[9 * a + b], v23[b], y1);
            y2 = fmaf(T2[9 * a + b], v23[b], y2);
            y3 = fmaf(T3[9 * a + b], v23[b], y3);
        }
        o0 = fmaf(v01[a], y0, o0);
        o1 = fmaf(v01[a], y1, o1);
        o2 = fmaf(v01[a], y2, o2);
        o3 = fmaf(v01[a], y3, o3);
    }

    reinterpret_cast<float4*>(out)[i] = make_float4(o0, o1, o2, o3);
}

extern "C" void kernel_launch(void* const* d_in, const int* in_sizes, int n_in,
                              void* d_out, int out_size, void* d_ws, size_t ws_size,
                              hipStream_t stream) {
    const float* patch  = (const float*)d_in[0];
    const float* params = (const float*)d_in[1];
    float* out = (float*)d_out;
    float* ws  = (float*)d_ws;
    const int B = in_sizes[0] / 4;

    vqc_setup<<<1, 128, 0, stream>>>(params, ws);

    const int block = 256;
    const int grid = (B + block - 1) / block;
    vqc_main<<<grid, block, 0, stream>>>(patch, params, ws, out, B);
}

// Round 5
// 79.271 us; speedup vs baseline: 1.1533x; 1.1533x over previous
//
#include <hip/hip_runtime.h>

// 4-qubit / 3-layer VQC, B = 2^20.
//
// Identity (verified R4): with merged angle th_w = patch_w + params[0,w,0],
// each output is EXACTLY multilinear in t_w = (1, cos th_w, sin th_w):
//     o_w = sum T^w[a,b,c,d] t0_a t1_b t2_c t3_d
// Setup kernel simulates the batch-uniform remainder of the circuit on the
// 3^4 grid th in {0, pi/2, pi} and inverts the evaluation map -> T.
// R5 changes vs R4:
//  - setup fully unrolled (compile-time masks), __sincosf, trig-in-LDS,
//    layer-2 RZ dropped  -> single-block latency cut ~10x.
//  - T stored interleaved as (T0,T1) and (T2,T3) pairs -> main kernel
//    accumulates float2 lanes -> v_pk_fma_f32 (packed), ~180 packed FMAs.

typedef float v2f __attribute__((ext_vector_type(2)));

// ws layout: [0..161]   pairs (T0[pos], T1[pos]) for pos = 0..80
//            [162..323] pairs (T2[pos], T3[pos])
// pos = 9*(3*d0+d1) + (3*d2+d3), digit d in {0,1,2} <-> basis (1, cos, sin)
__global__ void vqc_setup(const float* __restrict__ params,
                          float* __restrict__ ws) {
    __shared__ float trig[12][4];   // (cy, sy, cz, sz) half-angle per (l,w)
    __shared__ float bufA[81][4];
    __shared__ float bufB[81][4];
    const int tid = threadIdx.x;

    if (tid < 12) {
        float s, c;
        __sincosf(0.5f * params[tid * 2 + 0], &s, &c);
        trig[tid][0] = c; trig[tid][1] = s;
        __sincosf(0.5f * params[tid * 2 + 1], &s, &c);
        trig[tid][2] = c; trig[tid][3] = s;
    }
    __syncthreads();

    if (tid < 81) {
        const int d0 = tid / 27, d1 = (tid / 9) % 3, d2 = (tid / 3) % 3, d3 = tid % 3;
        const float chalf[3] = {1.0f, 0.70710678118654752f, 0.0f};
        const float shalf[3] = {0.0f, 0.70710678118654752f, 1.0f};
        const float ch[4] = {chalf[d0], chalf[d1], chalf[d2], chalf[d3]};
        const float sh[4] = {shalf[d0], shalf[d1], shalf[d2], shalf[d3]};

        // initial product state (grid angle already includes layer-0 RY)
        float re[16], im[16];
#pragma unroll
        for (int k = 0; k < 16; ++k) {
            float a = ((k >> 3) & 1) ? sh[0] : ch[0];
            a *= ((k >> 2) & 1) ? sh[1] : ch[1];
            a *= ((k >> 1) & 1) ? sh[2] : ch[2];
            a *= (k & 1) ? sh[3] : ch[3];
            re[k] = a; im[k] = 0.0f;
        }

        // ---- layer 0: RZ only ----
#pragma unroll
        for (int w = 0; w < 4; ++w) {
            const int m = 8 >> w;
            const float cz = trig[w][2], sz = trig[w][3];
#pragma unroll
            for (int k = 0; k < 16; ++k) {
                const float r = re[k], q = im[k];
                if (k & m) { re[k] = r * cz - q * sz; im[k] = q * cz + r * sz; }
                else       { re[k] = r * cz + q * sz; im[k] = q * cz - r * sz; }
            }
        }
#pragma unroll
        for (int w = 0; w < 3; ++w) {
            const int cm = 8 >> w, tm = 4 >> w;
#pragma unroll
            for (int b = 0; b < 16; ++b) {
                if ((b & cm) && !(b & tm)) {
                    const int j = b | tm;
                    float t = re[b]; re[b] = re[j]; re[j] = t;
                    t = im[b]; im[b] = im[j]; im[j] = t;
                }
            }
        }

        // ---- layers 1, 2 (layer-2 RZ dropped: probability-invariant) ----
#pragma unroll
        for (int l = 1; l < 3; ++l) {
#pragma unroll
            for (int w = 0; w < 4; ++w) {
                const int m = 8 >> w, g = l * 4 + w;
                const float cy = trig[g][0], sy = trig[g][1];
#pragma unroll
                for (int b = 0; b < 16; ++b) {
                    if (b & m) continue;
                    const int j = b | m;
                    const float r0 = re[b], r1 = re[j];
                    const float i0 = im[b], i1 = im[j];
                    re[b] = cy * r0 - sy * r1;  re[j] = sy * r0 + cy * r1;
                    im[b] = cy * i0 - sy * i1;  im[j] = sy * i0 + cy * i1;
                }
                if (l != 2) {
                    const float cz = trig[g][2], sz = trig[g][3];
#pragma unroll
                    for (int k = 0; k < 16; ++k) {
                        const float r = re[k], q = im[k];
                        if (k & m) { re[k] = r * cz - q * sz; im[k] = q * cz + r * sz; }
                        else       { re[k] = r * cz + q * sz; im[k] = q * cz - r * sz; }
                    }
                }
            }
#pragma unroll
            for (int w = 0; w < 3; ++w) {
                const int cm = 8 >> w, tm = 4 >> w;
#pragma unroll
                for (int b = 0; b < 16; ++b) {
                    if ((b & cm) && !(b & tm)) {
                        const int j = b | tm;
                        float t = re[b]; re[b] = re[j]; re[j] = t;
                        t = im[b]; im[b] = im[j]; im[j] = t;
                    }
                }
            }
        }

        float ev0 = 0.f, ev1 = 0.f, ev2 = 0.f, ev3 = 0.f;
#pragma unroll
        for (int k = 0; k < 16; ++k) {
            const float pk = re[k] * re[k] + im[k] * im[k];
            ev0 += (k & 8) ? -pk : pk;
            ev1 += (k & 4) ? -pk : pk;
            ev2 += (k & 2) ? -pk : pk;
            ev3 += (k & 1) ? -pk : pk;
        }
        bufA[tid][0] = ev0; bufA[tid][1] = ev1;
        bufA[tid][2] = ev2; bufA[tid][3] = ev3;
    }
    __syncthreads();

    // ---- invert evaluation map mode-by-mode ----
    // nodes {0, pi/2, pi} -> rows (1,1,0),(1,0,1),(1,-1,0);
    // Minv = [[.5,0,.5],[.5,0,-.5],[-.5,1,-.5]]
    const float Minv[3][3] = {{0.5f, 0.0f, 0.5f},
                              {0.5f, 0.0f, -0.5f},
                              {-0.5f, 1.0f, -0.5f}};
    const int strides[4] = {27, 9, 3, 1};
#pragma unroll
    for (int mo = 0; mo < 4; ++mo) {
        const int st = strides[mo];
        float (*src)[4] = (mo & 1) ? bufB : bufA;
        float (*dst)[4] = (mo & 1) ? bufA : bufB;
        for (int idx = tid; idx < 324; idx += blockDim.x) {
            const int w = idx & 3, pos = idx >> 2;
            const int dm = (pos / st) % 3;
            const int base = pos - dm * st;
            const float v = Minv[dm][0] * src[base][w]
                          + Minv[dm][1] * src[base + st][w]
                          + Minv[dm][2] * src[base + 2 * st][w];
            if (mo == 3) {
                // interleave: (T0,T1) pairs then (T2,T3) pairs
                const int half = (w >> 1);          // 0 for T0/T1, 1 for T2/T3
                ws[half * 162 + pos * 2 + (w & 1)] = v;
            } else {
                dst[pos][w] = v;
            }
        }
        __syncthreads();
    }
}

__global__ __launch_bounds__(256) void vqc_main(const float* __restrict__ patch,
                                                const float* __restrict__ params,
                                                const float* __restrict__ ws,
                                                float* __restrict__ out,
                                                const int B) {
    const int i = blockIdx.x * blockDim.x + threadIdx.x;
    if (i >= B) return;

    const float4 p = reinterpret_cast<const float4*>(patch)[i];

    float c0, s0, c1, s1, c2, s2, c3, s3;
    __sincosf(p.x + params[0], &s0, &c0);
    __sincosf(p.y + params[2], &s1, &c1);
    __sincosf(p.z + params[4], &s2, &c2);
    __sincosf(p.w + params[6], &s3, &c3);

    float v01[9], v23[9];
    v01[0] = 1.0f; v01[1] = c1;      v01[2] = s1;
    v01[3] = c0;   v01[4] = c0 * c1; v01[5] = c0 * s1;
    v01[6] = s0;   v01[7] = s0 * c1; v01[8] = s0 * s1;
    v23[0] = 1.0f; v23[1] = c3;      v23[2] = s3;
    v23[3] = c2;   v23[4] = c2 * c3; v23[5] = c2 * s3;
    v23[6] = s2;   v23[7] = s2 * c3; v23[8] = s2 * s3;

    const v2f* __restrict__ TA = reinterpret_cast<const v2f*>(ws);        // (T0,T1)
    const v2f* __restrict__ TB = reinterpret_cast<const v2f*>(ws + 162);  // (T2,T3)

    v2f o01 = {0.f, 0.f}, o23 = {0.f, 0.f};
#pragma unroll
    for (int a = 0; a < 9; ++a) {
        v2f y01 = {0.f, 0.f}, y23 = {0.f, 0.f};
#pragma unroll
        for (int b = 0; b < 9; ++b) {
            y01 += TA[9 * a + b] * v23[b];   // v_pk_fma_f32
            y23 += TB[9 * a + b] * v23[b];
        }
        o01 += v01[a] * y01;
        o23 += v01[a] * y23;
    }

    reinterpret_cast<float4*>(out)[i] = make_float4(o01.x, o01.y, o23.x, o23.y);
}

extern "C" void kernel_launch(void* const* d_in, const int* in_sizes, int n_in,
                              void* d_out, int out_size, void* d_ws, size_t ws_size,
                              hipStream_t stream) {
    const float* patch  = (const float*)d_in[0];
    const float* params = (const float*)d_in[1];
    float* out = (float*)d_out;
    float* ws  = (float*)d_ws;
    const int B = in_sizes[0] / 4;

    vqc_setup<<<1, 128, 0, stream>>>(params, ws);

    const int block = 256;
    const int grid = (B + block - 1) / block;
    vqc_main<<<grid, block, 0, stream>>>(patch, params, ws, out, B);
}